// Round 8
// baseline (147.282 us; speedup 1.0000x reference)
//
#include <hip/hip_runtime.h>
#include <hip/hip_fp16.h>

// Fused EdgeNetwork, 2-deep software-pipelined persistent waves.
//   OUT = P @ W on MFMA:  P[e, b*32+j] = bond[e,b]*nb[e,j]  (b=16 -> bias row)
//   W[b*32+j, i] = K[b, i*32+j]  held in 68 VGPRs per wave (col-half split).
// R8 change vs R7: epilogue uses packed-f16 atomics (global_atomic_pk_add_f16)
// into an f16 accumulator in ws -- halves atomic-op count (12.8M -> 6.4M) to
// test/break the TCC atomic-rate wall. k_final converts f16 acc -> f32 out.

typedef _Float16 half8 __attribute__((ext_vector_type(8)));
typedef _Float16 half4t __attribute__((ext_vector_type(4)));
typedef _Float16 half2t __attribute__((ext_vector_type(2)));
typedef float float4v __attribute__((ext_vector_type(4)));

constexpr int NA = 100000;
constexpr int E  = 400000;
constexpr int TILES = E / 32;          // 12500
constexpr int NBLK  = 1536;
constexpr int HALFW = NBLK * 4 / 2;    // 3072 waves per column-half

constexpr size_t OFF_ATOMH = 0;                          // _Float16[NA*32] (6.4 MB)
constexpr size_t OFF_BONDH = (size_t)NA * 32 * 2;        // _Float16[E*16] (12.8 MB)
constexpr size_t OFF_ACCH  = OFF_BONDH + (size_t)E * 16 * 2; // _Float16[NA*32] (6.4 MB)

constexpr int NACC4 = NA * 32 / 8;  // acch zeroing in float4 (8 halves) units: 400000
constexpr int NA4   = NA * 32 / 4;  // atom convert, float4 units
constexpr int NB4   = E * 16 / 4;   // bond convert, float4 units
constexpr int PREP_TOT = NACC4 + NA4 + NB4;

__global__ void k_prep(const float* __restrict__ atom,
                       const float* __restrict__ bond,
                       float4* __restrict__ acchz,
                       half4t* __restrict__ atomh4,
                       half4t* __restrict__ bondh4) {
  int i = blockIdx.x * blockDim.x + threadIdx.x;
  if (i < NACC4) {
    acchz[i] = make_float4(0.f, 0.f, 0.f, 0.f);
  } else if (i < NACC4 + NA4) {
    int k = i - NACC4;
    float4 v = ((const float4*)atom)[k];
    half4t hh = { (_Float16)v.x, (_Float16)v.y, (_Float16)v.z, (_Float16)v.w };
    atomh4[k] = hh;
  } else if (i < PREP_TOT) {
    int k = i - NACC4 - NA4;
    float4 v = ((const float4*)bond)[k];
    half4t hh = { (_Float16)v.x, (_Float16)v.y, (_Float16)v.z, (_Float16)v.w };
    bondh4[k] = hh;
  }
}

__global__ void k_final(const __half2* __restrict__ acch2, float2* __restrict__ out2) {
  int i = blockIdx.x * blockDim.x + threadIdx.x;
  if (i < NA * 16) {
    out2[i] = __half22float2(acch2[i]);
  }
}

static __device__ inline half8 splat8(_Float16 v) {
  half8 r = {v, v, v, v, v, v, v, v};
  return r;
}

__global__ __launch_bounds__(256, 3)
void edge_fused(const _Float16* __restrict__ atomh,
                const _Float16* __restrict__ bondh,
                const int* __restrict__ pairs,
                const float* __restrict__ Kmat,
                const float* __restrict__ bias,
                _Float16* __restrict__ acch)
{
  const int tid  = threadIdx.x;
  const int lane = tid & 63;
  const int wid  = blockIdx.x * 4 + (tid >> 6);
  const int h    = wid & 1;          // column half this wave owns
  const int q    = lane >> 4;
  const int el   = lane & 15;
  const int n    = el + h * 16;      // output column
  const int j0   = q * 8;

  // W fragments for all 17 K-steps, register-resident.
  half8 Wr[17];
  #pragma unroll
  for (int s = 0; s < 17; ++s) {
    const float* src = (s < 16) ? (Kmat + s * 1024 + n * 32 + j0)
                                : (bias + n * 32 + j0);
    half8 w;
    #pragma unroll
    for (int j = 0; j < 8; ++j) w[j] = (_Float16)src[j];
    Wr[s] = w;
  }

  const int start  = wid >> 1;
  const int stride = HALFW;
  const int2* pairs2 = (const int2*)pairs;

  auto ldpv = [&](int t) -> int2 {
    const int tc = t < TILES ? t : TILES - 1;   // clamp: loads stay valid
    int2 v = make_int2(0, 0);
    if (lane < 32) v = pairs2[tc * 32 + lane];
    return v;
  };

  if (start >= TILES) return;

  // ---- Pipeline prologue.
  int2 pv0 = ldpv(start);
  int2 pv1 = ldpv(start + stride);

  half8 nbA_c, nbB_c, bA0_c, bA1_c, bB0_c, bB1_c;
  {
    const int aA = __shfl(pv0.y, el);
    const int aB = __shfl(pv0.y, el + 16);
    nbA_c = *(const half8*)(atomh + (size_t)aA * 32 + j0);
    nbB_c = *(const half8*)(atomh + (size_t)aB * 32 + j0);
    const _Float16* brA = bondh + (size_t)(start * 32 + el) * 16;
    const _Float16* brB = bondh + (size_t)(start * 32 + el + 16) * 16;
    bA0_c = *(const half8*)(brA);  bA1_c = *(const half8*)(brA + 8);
    bB0_c = *(const half8*)(brB);  bB1_c = *(const half8*)(brB + 8);
  }

  const bool evenLane = (lane & 1) == 0;

  for (int t = start; t < TILES; t += stride) {
    const int tn = t + stride;

    // ---- Stage next tile first (loads in flight across this tile's compute).
    half8 nbA_n, nbB_n, bA0_n, bA1_n, bB0_n, bB1_n;
    {
      const int aA = __shfl(pv1.y, el);
      const int aB = __shfl(pv1.y, el + 16);
      nbA_n = *(const half8*)(atomh + (size_t)aA * 32 + j0);
      nbB_n = *(const half8*)(atomh + (size_t)aB * 32 + j0);
      const int tc = tn < TILES ? tn : TILES - 1;
      const _Float16* brA = bondh + (size_t)(tc * 32 + el) * 16;
      const _Float16* brB = bondh + (size_t)(tc * 32 + el + 16) * 16;
      bA0_n = *(const half8*)(brA);  bA1_n = *(const half8*)(brA + 8);
      bB0_n = *(const half8*)(brB);  bB1_n = *(const half8*)(brB + 8);
    }
    const int2 pv2 = ldpv(tn + stride);

    // ---- Compute current tile.
    float4v acc0 = {0.f, 0.f, 0.f, 0.f};
    float4v acc1 = {0.f, 0.f, 0.f, 0.f};
    #pragma unroll
    for (int s = 0; s < 16; ++s) {
      const _Float16 sA = (s < 8) ? bA0_c[s] : bA1_c[s - 8];
      const _Float16 sB = (s < 8) ? bB0_c[s] : bB1_c[s - 8];
      const half8 aAf = nbA_c * splat8(sA);
      const half8 aBf = nbB_c * splat8(sB);
      acc0 = __builtin_amdgcn_mfma_f32_16x16x32_f16(aAf, Wr[s], acc0, 0, 0, 0);
      acc1 = __builtin_amdgcn_mfma_f32_16x16x32_f16(aBf, Wr[s], acc1, 0, 0, 0);
    }
    acc0 = __builtin_amdgcn_mfma_f32_16x16x32_f16(nbA_c, Wr[16], acc0, 0, 0, 0);
    acc1 = __builtin_amdgcn_mfma_f32_16x16x32_f16(nbB_c, Wr[16], acc1, 0, 0, 0);

    // ---- Epilogue: packed-f16 atomics. Lane pair (lane, lane^1) exchanges one
    // value so each lane owns a (col, col+1) pair: even lanes cover tile-A rows,
    // odd lanes cover tile-B rows. 4 pk-atomics/lane/tile (was 8 fp32 atomics).
    #pragma unroll
    for (int r = 0; r < 4; ++r) {
      const float pA = __shfl_xor(acc0[r], 1);   // partner's acc0
      const float pB = __shfl_xor(acc1[r], 1);   // partner's acc1
      const int s0 = __shfl(pv0.x, q * 4 + r);
      const int s1 = __shfl(pv0.x, q * 4 + r + 16);
      const int sdst = evenLane ? s0 : s1;
      const int col  = evenLane ? n : (n - 1);
      const float lo = evenLane ? acc0[r] : pB;
      const float hi = evenLane ? pA : acc1[r];
      half2t hv = { (_Float16)lo, (_Float16)hi };
      unsafeAtomicAdd((__half2*)(acch + (size_t)sdst * 32 + col),
                      __builtin_bit_cast(__half2, hv));
    }

    // ---- Rotate pipeline registers.
    pv0 = pv1; pv1 = pv2;
    nbA_c = nbA_n; nbB_c = nbB_n;
    bA0_c = bA0_n; bA1_c = bA1_n; bB0_c = bB0_n; bB1_c = bB1_n;
  }
}

extern "C" void kernel_launch(void* const* d_in, const int* in_sizes, int n_in,
                              void* d_out, int out_size, void* d_ws, size_t ws_size,
                              hipStream_t stream) {
  const float* atom  = (const float*)d_in[0];   // (100000, 32) f32
  const float* bondf = (const float*)d_in[1];   // (400000, 16) f32
  const int*   pairs = (const int*)d_in[2];     // (400000, 2) int32
  const float* Kmat  = (const float*)d_in[3];   // (16, 1024) f32
  const float* bias  = (const float*)d_in[4];   // (1024,) f32
  float* out = (float*)d_out;                   // (100000, 32) f32

  _Float16* atomh = (_Float16*)((char*)d_ws + OFF_ATOMH);
  _Float16* bondh = (_Float16*)((char*)d_ws + OFF_BONDH);
  _Float16* acch  = (_Float16*)((char*)d_ws + OFF_ACCH);

  k_prep<<<(PREP_TOT + 255) / 256, 256, 0, stream>>>(
      atom, bondf, (float4*)acch, (half4t*)atomh, (half4t*)bondh);
  edge_fused<<<NBLK, 256, 0, stream>>>(atomh, bondh, pairs, Kmat, bias, acch);
  k_final<<<(NA * 16 + 255) / 256, 256, 0, stream>>>((const __half2*)acch, (float2*)out);
}